// Round 11
// baseline (215.955 us; speedup 1.0000x reference)
//
#include <hip/hip_runtime.h>

// MultiHeadAttention forward, MI355X/gfx950.
// x[2,2048,1024] f32, mask[2,2048] i32, W_qkv[1024,3072], b_qkv[3072],
// W_proj[1024,1024], b_proj[1024] -> out[2,2048,1024] f32.
// Pipeline: convert/transpose -> QKV GEMM (bf16 MFMA, counted-vmcnt 3-buf) ->
// flash attn (32x32 swapped-QK^T, K-split x2 over 1024 blocks, 32KB LDS for
// 4 blocks/CU) -> combine (flash-merge of 2 halves) -> proj GEMM.

#define BATCH 2
#define SEQ 2048
#define DMODEL 1024
#define NHEADS 16
#define HDIM 64
#define BS (BATCH * SEQ)   // 4096
#define N3 (3 * DMODEL)    // 3072
// 0.125 (1/sqrt(64)) * log2(e): softmax computed base-2
#define QSCALE 0.18033688011112042f

typedef float f32x4 __attribute__((ext_vector_type(4)));
typedef float f32x16 __attribute__((ext_vector_type(16)));
typedef short bf16x8 __attribute__((ext_vector_type(8)));
typedef unsigned short u16;
typedef unsigned short u16x4 __attribute__((ext_vector_type(4)));

typedef const __attribute__((address_space(1))) unsigned int* gptr_t;
typedef __attribute__((address_space(3))) unsigned int* sptr_t;

__device__ __forceinline__ u16 f2bf(float f) {
  unsigned int u = __float_as_uint(f);
  return (u16)((u + 0x7fffu + ((u >> 16) & 1u)) >> 16);
}

__device__ __forceinline__ void gload_lds16(const void* g, void* l) {
  __builtin_amdgcn_global_load_lds((gptr_t)g, (sptr_t)l, 16, 0, 0);
}

__device__ __forceinline__ unsigned cvtpk(float lo, float hi) {
  unsigned r;
  asm("v_cvt_pk_bf16_f32 %0, %1, %2" : "=v"(r) : "v"(lo), "v"(hi));
  return r;
}

// After: d = {d.lo32, s.lo32}, s = {d.hi32, s.hi32} (half-wave exchange)
__device__ __forceinline__ void pl32swap(unsigned& d, unsigned& s) {
  asm volatile("v_permlane32_swap_b32 %0, %1" : "+v"(d), "+v"(s));
}

#define WAIT_VM4() asm volatile("s_waitcnt vmcnt(4)" ::: "memory")
#define WAIT_VM0() asm volatile("s_waitcnt vmcnt(0)" ::: "memory")

// ---------------- fp32 -> bf16 elementwise (x) ----------------
__global__ __launch_bounds__(256) void conv_x(const float* __restrict__ in,
                                              u16* __restrict__ out, int n4) {
  int i = blockIdx.x * 256 + threadIdx.x;
  if (i >= n4) return;
  float4 v = ((const float4*)in)[i];
  u16x4 o;
  o[0] = f2bf(v.x); o[1] = f2bf(v.y); o[2] = f2bf(v.z); o[3] = f2bf(v.w);
  ((u16x4*)out)[i] = o;
}

// ---------------- fp32 [R][C] -> bf16 [C][R] transpose ----------------
__global__ __launch_bounds__(256) void transp(const float* __restrict__ in,
                                              u16* __restrict__ out, int R, int C) {
  __shared__ float tile[64][65];
  int tx = threadIdx.x & 63, ty = threadIdx.x >> 6;
  int c0 = blockIdx.x * 64, r0 = blockIdx.y * 64;
#pragma unroll
  for (int j = ty; j < 64; j += 4)
    tile[j][tx] = in[(size_t)(r0 + j) * C + c0 + tx];
  __syncthreads();
#pragma unroll
  for (int j = ty; j < 64; j += 4)
    out[(size_t)(c0 + j) * R + r0 + tx] = f2bf(tile[tx][j]);
}

// ---------------- bf16 GEMM: C = A[M,K] @ Bt[N,K]^T + bias ----------------
// 128x128 tile, BK=32, 4 waves (2x2), mfma_f32_16x16x32_bf16.
// 3-buffer LDS, 2-deep prefetch, counted vmcnt + raw s_barrier, XCD swizzle.
// MODE 0: QKV epilogue (Q scaled->qkb, K->qkb, V->vtb transposed per head, bf16)
// MODE 1: proj epilogue (fp32 out + bias)
template <int MODE>
__global__ __launch_bounds__(256) void gemm_bt(
    const u16* __restrict__ A, const u16* __restrict__ Bt,
    const float* __restrict__ bias, float* __restrict__ outf,
    u16* __restrict__ qkb, u16* __restrict__ vtb, int M, int N, int K) {
  __shared__ __align__(16) u16 lds[3 * 2 * 4096];  // [buf][A/B][128*32] 48KB
  // bijective XCD-chunked block swizzle (nwg % 8 == 0 for all our grids)
  const int nwgx = gridDim.x;
  const int nwg = nwgx * gridDim.y;
  const int idx = blockIdx.y * nwgx + blockIdx.x;
  const int swz = (idx & 7) * (nwg >> 3) + (idx >> 3);
  const int m0 = (swz / nwgx) * 128, n0 = (swz % nwgx) * 128;

  const int tid = threadIdx.x;
  const int lane = tid & 63, w = tid >> 6;
  const int wr = w >> 1, wc = w & 1;
  const int lg = lane >> 4, lr = lane & 15;
  const int NK = K >> 5;

  f32x4 acc[4][4] = {};

  const int srow = tid >> 2;        // 0..63 staging row
  const int scb = (tid & 3) << 4;   // staging byte col 0..48
  const char* Abase = (const char*)A + ((size_t)(m0 + srow) * K) * 2 + scb;
  const char* Bbase = (const char*)Bt + ((size_t)(n0 + srow) * K) * 2 + scb;
  const size_t half = (size_t)64 * K * 2;

  auto stage = [&](int buf, int kk) {  // 4 VMEM ops per wave
    char* dst = (char*)lds + buf * 16384;
    const char* a = Abase + kk * 64;
    gload_lds16(a, dst + tid * 16);
    gload_lds16(a + half, dst + 4096 + tid * 16);
    const char* b = Bbase + kk * 64;
    gload_lds16(b, dst + 8192 + tid * 16);
    gload_lds16(b + half, dst + 12288 + tid * 16);
  };

  stage(0, 0);
  stage(1, 1);
  int bi = 0;
  for (int kk = 0; kk < NK; ++kk) {
    // stage(kk) is followed by exactly 4 VMEM ops (stage(kk+1)) when kk<NK-1.
    if (kk < NK - 1) WAIT_VM4(); else WAIT_VM0();
    __builtin_amdgcn_s_barrier();
    if (kk + 2 < NK) stage(bi == 0 ? 2 : bi - 1, kk + 2);
    const u16* lA = lds + bi * 8192;
    const u16* lB = lA + 4096;
    bf16x8 af[4], bfr[4];
#pragma unroll
    for (int i = 0; i < 4; ++i)
      af[i] = *(const bf16x8*)(lA + (wr * 64 + i * 16 + lr) * 32 + lg * 8);
#pragma unroll
    for (int j = 0; j < 4; ++j)
      bfr[j] = *(const bf16x8*)(lB + (wc * 64 + j * 16 + lr) * 32 + lg * 8);
#pragma unroll
    for (int i = 0; i < 4; ++i)
#pragma unroll
      for (int j = 0; j < 4; ++j)
        acc[i][j] = __builtin_amdgcn_mfma_f32_16x16x32_bf16(af[i], bfr[j],
                                                            acc[i][j], 0, 0, 0);
    bi = (bi == 2) ? 0 : bi + 1;
  }

  // epilogue: C row = m0+wr*64+i*16+lg*4+r, col = n0+wc*64+j*16+lr
#pragma unroll
  for (int i = 0; i < 4; ++i) {
    const int rowb = m0 + wr * 64 + i * 16 + lg * 4;
#pragma unroll
    for (int j = 0; j < 4; ++j) {
      const int col = n0 + wc * 64 + j * 16 + lr;
      const float bv = bias[col];
      if (MODE == 0) {
        if (col < 2 * DMODEL) {
          const float qs = (col < DMODEL) ? QSCALE : 1.0f;
#pragma unroll
          for (int r = 0; r < 4; ++r)
            qkb[(size_t)(rowb + r) * (2 * DMODEL) + col] =
                f2bf((acc[i][j][r] + bv) * qs);
        } else {
          const int hd = col - 2 * DMODEL;
          const int b = rowb >> 11, s0 = rowb & (SEQ - 1);
          u16x4 pk;
#pragma unroll
          for (int r = 0; r < 4; ++r) pk[r] = f2bf(acc[i][j][r] + bv);
          *(u16x4*)(vtb +
                    ((size_t)((b * NHEADS + (hd >> 6)) * HDIM + (hd & 63))) * SEQ +
                    s0) = pk;
        }
      } else {
#pragma unroll
        for (int r = 0; r < 4; ++r)
          outf[(size_t)(rowb + r) * N + col] = acc[i][j][r] + bv;
      }
    }
  }
}

// ---------------- flash attention, 32x32 swapped-QK^T, K-split x2 ----------
// grid 1024 swizzled (q-tile 128 x 16 heads x 2 batch x 2 K-halves), 256 thr.
// qkb: [4096][2048] bf16 (Qscaled | K), vtb: [B][H][64][SEQ] bf16 (V^T).
// Per lane: one q-row (q = lane&31), hi = lane>>5 selects k-halves.
// Each block does 16 KV tiles (its half); partial ctx^T (f32) + (m,l) out.
// K/V double-buffered (32KB -> 4 blocks/CU); per iter:
//   stage(t+1); vmcnt(4); barrier; compute(t); barrier.
__global__ __launch_bounds__(256) void attn(const u16* __restrict__ qkb,
                                            const u16* __restrict__ vtb,
                                            const int* __restrict__ mask,
                                            float* __restrict__ ctxp,
                                            float* __restrict__ ml) {
  __shared__ __align__(16) u16 Kl[2][64 * 64];  // 16KB (swizzled rows)
  __shared__ __align__(16) u16 Vl[2][64 * 64];  // 16KB (swizzled rows)

  // XCD-chunked swizzle over 1024 blocks: q0(16) fastest, h(16), b*half(4)
  const int idx = (blockIdx.z * gridDim.y + blockIdx.y) * gridDim.x + blockIdx.x;
  const int swz = (idx & 7) * 128 + (idx >> 3);
  const int q0 = (swz & 15) * 128;
  const int h = (swz >> 4) & 15;
  const int bh = swz >> 8;         // 0..3
  const int b = bh >> 1;
  const int khalf = bh & 1;

  const int tid = threadIdx.x;
  const int lane = tid & 63, w = tid >> 6;
  const int qi = lane & 31;            // lane's q-row
  const int hi = lane >> 5;            // half-wave (k-split within tile)
  const int q = q0 + w * 32 + qi;

  // ---- mask prescan, register-only: any zero in this batch row? ----
  bool anyz;
  {
    const int4* mrow = (const int4*)(mask + b * SEQ);
    int z = 0;
#pragma unroll
    for (int p = 0; p < 8; ++p) {
      int4 m = mrow[lane + p * 64];
      z |= (m.x == 0) | (m.y == 0) | (m.z == 0) | (m.w == 0);
    }
    anyz = __any(z);
  }

  // Q regs: B-operand fragments over d (4 chunks of K=16)
  bf16x8 qreg[4];
  {
    const u16* Qrow = qkb + (size_t)(b * SEQ + q) * (2 * DMODEL) + h * HDIM;
#pragma unroll
    for (int kc = 0; kc < 4; ++kc)
      qreg[kc] = *(const bf16x8*)(Qrow + kc * 16 + hi * 8);
  }

  float m_run = -3.0e38f, l_run = 0.f;
  f32x16 ct0 = (f32x16)0.f, ct1 = (f32x16)0.f;   // ctx^T: d=qi(+32), cols=q

  const u16* Kg = qkb + (size_t)(b * SEQ) * (2 * DMODEL) + DMODEL + h * HDIM;
  const u16* Vg = vtb + (size_t)((b * NHEADS + h) * HDIM) * SEQ;
  const int srow = tid >> 3;                          // staging row 0..31 (+32)
  const int scol = ((tid & 7) ^ (srow & 7)) << 4;     // pre-swizzled src byte col

  auto stage = [&](int t) {  // 4 VMEM ops per wave; buf = t&1
    const int buf = t & 1;
    const int k0 = t * 64;
    const char* ks = (const char*)(Kg + (size_t)(k0 + srow) * (2 * DMODEL)) + scol;
    gload_lds16(ks, (char*)Kl[buf] + tid * 16);
    gload_lds16(ks + (size_t)32 * (2 * DMODEL) * 2,
                (char*)Kl[buf] + 4096 + tid * 16);
    const char* vs = (const char*)(Vg + (size_t)srow * SEQ + k0) + scol;
    gload_lds16(vs, (char*)Vl[buf] + tid * 16);
    gload_lds16(vs + (size_t)32 * SEQ * 2, (char*)Vl[buf] + 4096 + tid * 16);
  };

  auto compute = [&](int t, bool use_mask) {
    const int buf = t & 1;
    // ---- QK^T (swapped): s0 keys 0-31, s1 keys 32-63; col = q = qi ----
    f32x16 s0 = (f32x16)0.f, s1 = (f32x16)0.f;
    const char* Kb = (const char*)Kl[buf];
    __builtin_amdgcn_s_setprio(1);
#pragma unroll
    for (int kc = 0; kc < 4; ++kc) {
      const int sl = (((kc << 1) | hi) ^ (lane & 7)) << 4;
      bf16x8 kf0 = *(const bf16x8*)(Kb + qi * 128 + sl);
      bf16x8 kf1 = *(const bf16x8*)(Kb + (32 + qi) * 128 + sl);
      s0 = __builtin_amdgcn_mfma_f32_32x32x16_bf16(kf0, qreg[kc], s0, 0, 0, 0);
      s1 = __builtin_amdgcn_mfma_f32_32x32x16_bf16(kf1, qreg[kc], s1, 0, 0, 0);
    }
    __builtin_amdgcn_s_setprio(0);

    if (use_mask) {
      const int base = b * SEQ + t * 64;
#pragma unroll
      for (int r = 0; r < 16; ++r) {
        const int key = (r & 3) + 8 * (r >> 2) + 4 * hi;
        if (mask[base + key] == 0) s0[r] = -3.0e38f;
        if (mask[base + 32 + key] == 0) s1[r] = -3.0e38f;
      }
    }

    // ---- online softmax (base-2), scalar per-lane state, defer-max ----
    float pm = fmaxf(fmaxf(s0[0], s0[1]), s0[2]);
#pragma unroll
    for (int r = 3; r < 16; r += 2) pm = fmaxf(fmaxf(pm, s0[r]), s0[r + 1]);
#pragma unroll
    for (int r = 0; r < 16; r += 2) pm = fmaxf(fmaxf(pm, s1[r]), s1[r + 1]);
    pm = fmaxf(pm, __shfl_xor(pm, 32));
    if (__any(pm > m_run + 8.f)) {
      const float mn = fmaxf(m_run, pm);
      const float corr = __builtin_amdgcn_exp2f(m_run - mn);
      m_run = mn;
      l_run *= corr;
#pragma unroll
      for (int r = 0; r < 16; ++r) { ct0[r] *= corr; ct1[r] *= corr; }
    }
    float ls = 0.f;
#pragma unroll
    for (int r = 0; r < 16; ++r) {
      s0[r] = __builtin_amdgcn_exp2f(s0[r] - m_run); ls += s0[r];
    }
#pragma unroll
    for (int r = 0; r < 16; ++r) {
      s1[r] = __builtin_amdgcn_exp2f(s1[r] - m_run); ls += s1[r];
    }
    l_run += ls + __shfl_xor(ls, 32);

    // ---- P -> bf16 pairs; PV: ctx^T += V^T * P^T ----
    unsigned pk[16];
#pragma unroll
    for (int rp = 0; rp < 8; ++rp) {
      pk[rp] = cvtpk(s0[2 * rp], s0[2 * rp + 1]);
      pk[8 + rp] = cvtpk(s1[2 * rp], s1[2 * rp + 1]);
    }
    const char* Vb = (const char*)Vl[buf];
    __builtin_amdgcn_s_setprio(1);
#pragma unroll
    for (int ks = 0; ks < 4; ++ks) {
      const int mb = (ks >> 1) * 8 + (ks & 1) * 4;
      unsigned b0 = pk[mb + 0], b2 = pk[mb + 2];
      unsigned b1 = pk[mb + 1], b3 = pk[mb + 3];
      pl32swap(b0, b2);   // b0 = both lo-halves, b2 = both hi-halves
      pl32swap(b1, b3);
      union { unsigned u[4]; bf16x8 v; } bu;
      bu.u[0] = b0; bu.u[1] = b1; bu.u[2] = b2; bu.u[3] = b3;
      const int sl = (((ks << 1) | hi) ^ (lane & 7)) << 4;
      bf16x8 vf0 = *(const bf16x8*)(Vb + qi * 128 + sl);
      bf16x8 vf1 = *(const bf16x8*)(Vb + (32 + qi) * 128 + sl);
      ct0 = __builtin_amdgcn_mfma_f32_32x32x16_bf16(vf0, bu.v, ct0, 0, 0, 0);
      ct1 = __builtin_amdgcn_mfma_f32_32x32x16_bf16(vf1, bu.v, ct1, 0, 0, 0);
    }
    __builtin_amdgcn_s_setprio(0);
  };

  const int t0 = khalf * 16, tend = t0 + 16;
  stage(t0);
  if (!anyz) {
    // fast path: counted vmcnt; wait BEFORE barrier so all waves' stage(t)
    // is proven landed after the barrier.
    for (int t = t0; t < tend; ++t) {
      if (t + 1 < tend) { stage(t + 1); WAIT_VM4(); } else { WAIT_VM0(); }
      __builtin_amdgcn_s_barrier();
      compute(t, false);
      __builtin_amdgcn_s_barrier();   // all reads of buf[t&1] done
    }
  } else {
    // slow path (masked): conservative full drains
    for (int t = t0; t < tend; ++t) {
      __syncthreads();
      if (t + 1 < tend) stage(t + 1);
      __syncthreads();  // drains vmcnt(0) -> stage(t) and earlier complete
      compute(t, true);
    }
  }

  // ---- epilogue: partial ctx^T (f32, un-normalized) + (m,l) ----
  float* orow = ctxp + ((size_t)(khalf * BS + b * SEQ + q)) * DMODEL + h * HDIM;
#pragma unroll
  for (int g = 0; g < 4; ++g) {
    {
      float4 st = make_float4(ct0[4 * g], ct0[4 * g + 1], ct0[4 * g + 2],
                              ct0[4 * g + 3]);
      *(float4*)(orow + 8 * g + 4 * hi) = st;
    }
    {
      float4 st = make_float4(ct1[4 * g], ct1[4 * g + 1], ct1[4 * g + 2],
                              ct1[4 * g + 3]);
      *(float4*)(orow + 32 + 8 * g + 4 * hi) = st;
    }
  }
  if (hi == 0) {
    float* mlp = ml + ((size_t)(khalf * BS + b * SEQ + q) * NHEADS + h) * 2;
    mlp[0] = m_run;
    mlp[1] = l_run;
  }
}

// ---------------- combine: flash-merge the two K-halves ----------------
// thread -> (token, 8 dims). ctx = (c0*w0 + c1*w1) / (l0*w0 + l1*w1).
__global__ __launch_bounds__(256) void combine(const float* __restrict__ ctxp,
                                               const float* __restrict__ ml,
                                               u16* __restrict__ ctxb) {
  const int gid = blockIdx.x * 256 + threadIdx.x;
  const int token = gid >> 7;
  const int d0 = (gid & 127) << 3;
  const int h = d0 >> 6;
  const float2 ml0 = *(const float2*)(ml + ((size_t)token * NHEADS + h) * 2);
  const float2 ml1 =
      *(const float2*)(ml + ((size_t)(BS + token) * NHEADS + h) * 2);
  const float M = fmaxf(ml0.x, ml1.x);
  const float w0 = exp2f(ml0.x - M), w1 = exp2f(ml1.x - M);
  const float rl = __builtin_amdgcn_rcpf(ml0.y * w0 + ml1.y * w1);
  const float4* c0 = (const float4*)(ctxp + (size_t)token * DMODEL + d0);
  const float4* c1 =
      (const float4*)(ctxp + ((size_t)BS + token) * DMODEL + d0);
  uint4 st;
  {
    float4 a = c0[0], v = c1[0];
    st.x = cvtpk((a.x * w0 + v.x * w1) * rl, (a.y * w0 + v.y * w1) * rl);
    st.y = cvtpk((a.z * w0 + v.z * w1) * rl, (a.w * w0 + v.w * w1) * rl);
  }
  {
    float4 a = c0[1], v = c1[1];
    st.z = cvtpk((a.x * w0 + v.x * w1) * rl, (a.y * w0 + v.y * w1) * rl);
    st.w = cvtpk((a.z * w0 + v.z * w1) * rl, (a.w * w0 + v.w * w1) * rl);
  }
  *(uint4*)(ctxb + (size_t)token * DMODEL + d0) = st;
}

extern "C" void kernel_launch(void* const* d_in, const int* in_sizes, int n_in,
                              void* d_out, int out_size, void* d_ws, size_t ws_size,
                              hipStream_t stream) {
  const float* x = (const float*)d_in[0];
  const int* mask = (const int*)d_in[1];
  const float* Wqkv = (const float*)d_in[2];
  const float* bqkv = (const float*)d_in[3];
  const float* Wproj = (const float*)d_in[4];
  const float* bproj = (const float*)d_in[5];
  float* out = (float*)d_out;

  char* ws = (char*)d_ws;
  u16* xb = (u16*)(ws);                       // 4096*1024 bf16      (8 MB)
  u16* wqkvt = (u16*)(ws + 8388608);          // [3072][1024] bf16   (6 MB)
  u16* wprojt = (u16*)(ws + 14680064);        // [1024][1024] bf16   (2 MB)
  u16* qkb = (u16*)(ws + 16777216);           // [4096][2048] bf16   (16 MB)
  u16* vtb = (u16*)(ws + 33554432);           // [B][H][64][2048]    (8 MB)
  u16* ctxb = (u16*)(ws + 41943040);          // [4096][1024] bf16   (8 MB)
  float* ctxp = (float*)(ws + 50331648);      // [2][4096][1024] f32 (32 MB)
  float* ml = (float*)(ws + 83886080);        // [2][4096][16][2] f32 (1 MB)

  conv_x<<<dim3((BS * DMODEL / 4 + 255) / 256), 256, 0, stream>>>(x, xb,
                                                                  BS * DMODEL / 4);
  transp<<<dim3(N3 / 64, DMODEL / 64), 256, 0, stream>>>(Wqkv, wqkvt, DMODEL, N3);
  transp<<<dim3(DMODEL / 64, DMODEL / 64), 256, 0, stream>>>(Wproj, wprojt, DMODEL,
                                                             DMODEL);
  gemm_bt<0><<<dim3(N3 / 128, BS / 128), 256, 0, stream>>>(
      xb, wqkvt, bqkv, nullptr, qkb, vtb, BS, N3, DMODEL);
  attn<<<dim3(SEQ / 128, NHEADS, BATCH * 2), 256, 0, stream>>>(qkb, vtb, mask,
                                                               ctxp, ml);
  combine<<<dim3(BS * DMODEL / 8 / 256), 256, 0, stream>>>(ctxp, ml, ctxb);
  gemm_bt<1><<<dim3(DMODEL / 128, BS / 128), 256, 0, stream>>>(
      ctxb, wprojt, bproj, out, nullptr, nullptr, BS, DMODEL, DMODEL);
}

// Round 12
// 198.695 us; speedup vs baseline: 1.0869x; 1.0869x over previous
//
#include <hip/hip_runtime.h>

// MultiHeadAttention forward, MI355X/gfx950.
// x[2,2048,1024] f32, mask[2,2048] i32, W_qkv[1024,3072], b_qkv[3072],
// W_proj[1024,1024], b_proj[1024] -> out[2,2048,1024] f32.
// Pipeline: convert/transpose -> QKV GEMM (bf16 MFMA, counted-vmcnt 3-buf,
// 4 waves) -> flash attn (32x32 swapped-QK^T, sw-pipelined, 60.7us measured)
// -> proj GEMM (8 waves for 2/SIMD occupancy; was 1/SIMD).

#define BATCH 2
#define SEQ 2048
#define DMODEL 1024
#define NHEADS 16
#define HDIM 64
#define BS (BATCH * SEQ)   // 4096
#define N3 (3 * DMODEL)    // 3072
// 0.125 (1/sqrt(64)) * log2(e): softmax computed base-2
#define QSCALE 0.18033688011112042f

typedef float f32x4 __attribute__((ext_vector_type(4)));
typedef float f32x16 __attribute__((ext_vector_type(16)));
typedef short bf16x8 __attribute__((ext_vector_type(8)));
typedef unsigned short u16;
typedef unsigned short u16x4 __attribute__((ext_vector_type(4)));

typedef const __attribute__((address_space(1))) unsigned int* gptr_t;
typedef __attribute__((address_space(3))) unsigned int* sptr_t;

__device__ __forceinline__ u16 f2bf(float f) {
  unsigned int u = __float_as_uint(f);
  return (u16)((u + 0x7fffu + ((u >> 16) & 1u)) >> 16);
}

__device__ __forceinline__ void gload_lds16(const void* g, void* l) {
  __builtin_amdgcn_global_load_lds((gptr_t)g, (sptr_t)l, 16, 0, 0);
}

__device__ __forceinline__ unsigned cvtpk(float lo, float hi) {
  unsigned r;
  asm("v_cvt_pk_bf16_f32 %0, %1, %2" : "=v"(r) : "v"(lo), "v"(hi));
  return r;
}

// After: d = {d.lo32, s.lo32}, s = {d.hi32, s.hi32} (half-wave exchange)
__device__ __forceinline__ void pl32swap(unsigned& d, unsigned& s) {
  asm volatile("v_permlane32_swap_b32 %0, %1" : "+v"(d), "+v"(s));
}

#define WAIT_VM4() asm volatile("s_waitcnt vmcnt(4)" ::: "memory")
#define WAIT_VM2() asm volatile("s_waitcnt vmcnt(2)" ::: "memory")
#define WAIT_VM0() asm volatile("s_waitcnt vmcnt(0)" ::: "memory")

// ---------------- fp32 -> bf16 elementwise (x) ----------------
__global__ __launch_bounds__(256) void conv_x(const float* __restrict__ in,
                                              u16* __restrict__ out, int n4) {
  int i = blockIdx.x * 256 + threadIdx.x;
  if (i >= n4) return;
  float4 v = ((const float4*)in)[i];
  u16x4 o;
  o[0] = f2bf(v.x); o[1] = f2bf(v.y); o[2] = f2bf(v.z); o[3] = f2bf(v.w);
  ((u16x4*)out)[i] = o;
}

// ---------------- fp32 [R][C] -> bf16 [C][R] transpose ----------------
__global__ __launch_bounds__(256) void transp(const float* __restrict__ in,
                                              u16* __restrict__ out, int R, int C) {
  __shared__ float tile[64][65];
  int tx = threadIdx.x & 63, ty = threadIdx.x >> 6;
  int c0 = blockIdx.x * 64, r0 = blockIdx.y * 64;
#pragma unroll
  for (int j = ty; j < 64; j += 4)
    tile[j][tx] = in[(size_t)(r0 + j) * C + c0 + tx];
  __syncthreads();
#pragma unroll
  for (int j = ty; j < 64; j += 4)
    out[(size_t)(c0 + j) * R + r0 + tx] = f2bf(tile[tx][j]);
}

// ---------------- bf16 GEMM: C = A[M,K] @ Bt[N,K]^T + bias (QKV) ----------
// 128x128 tile, BK=32, 4 waves (2x2), mfma_f32_16x16x32_bf16.
// 3-buffer LDS, 2-deep prefetch, counted vmcnt + raw s_barrier, XCD swizzle.
// Epilogue: Q scaled->qkb, K->qkb, V->vtb transposed per head (bf16).
__global__ __launch_bounds__(256) void gemm_qkv(
    const u16* __restrict__ A, const u16* __restrict__ Bt,
    const float* __restrict__ bias, u16* __restrict__ qkb,
    u16* __restrict__ vtb, int M, int N, int K) {
  __shared__ __align__(16) u16 lds[3 * 2 * 4096];  // [buf][A/B][128*32] 48KB
  const int nwgx = gridDim.x;
  const int nwg = nwgx * gridDim.y;
  const int idx = blockIdx.y * nwgx + blockIdx.x;
  const int swz = (idx & 7) * (nwg >> 3) + (idx >> 3);
  const int m0 = (swz / nwgx) * 128, n0 = (swz % nwgx) * 128;

  const int tid = threadIdx.x;
  const int lane = tid & 63, w = tid >> 6;
  const int wr = w >> 1, wc = w & 1;
  const int lg = lane >> 4, lr = lane & 15;
  const int NK = K >> 5;

  f32x4 acc[4][4] = {};

  const int srow = tid >> 2;        // 0..63 staging row
  const int scb = (tid & 3) << 4;   // staging byte col 0..48
  const char* Abase = (const char*)A + ((size_t)(m0 + srow) * K) * 2 + scb;
  const char* Bbase = (const char*)Bt + ((size_t)(n0 + srow) * K) * 2 + scb;
  const size_t half = (size_t)64 * K * 2;

  auto stage = [&](int buf, int kk) {  // 4 VMEM ops per wave
    char* dst = (char*)lds + buf * 16384;
    const char* a = Abase + kk * 64;
    gload_lds16(a, dst + tid * 16);
    gload_lds16(a + half, dst + 4096 + tid * 16);
    const char* b = Bbase + kk * 64;
    gload_lds16(b, dst + 8192 + tid * 16);
    gload_lds16(b + half, dst + 12288 + tid * 16);
  };

  stage(0, 0);
  stage(1, 1);
  int bi = 0;
  for (int kk = 0; kk < NK; ++kk) {
    if (kk < NK - 1) WAIT_VM4(); else WAIT_VM0();
    __builtin_amdgcn_s_barrier();
    if (kk + 2 < NK) stage(bi == 0 ? 2 : bi - 1, kk + 2);
    const u16* lA = lds + bi * 8192;
    const u16* lB = lA + 4096;
    bf16x8 af[4], bfr[4];
#pragma unroll
    for (int i = 0; i < 4; ++i)
      af[i] = *(const bf16x8*)(lA + (wr * 64 + i * 16 + lr) * 32 + lg * 8);
#pragma unroll
    for (int j = 0; j < 4; ++j)
      bfr[j] = *(const bf16x8*)(lB + (wc * 64 + j * 16 + lr) * 32 + lg * 8);
#pragma unroll
    for (int i = 0; i < 4; ++i)
#pragma unroll
      for (int j = 0; j < 4; ++j)
        acc[i][j] = __builtin_amdgcn_mfma_f32_16x16x32_bf16(af[i], bfr[j],
                                                            acc[i][j], 0, 0, 0);
    bi = (bi == 2) ? 0 : bi + 1;
  }

  // epilogue: C row = m0+wr*64+i*16+lg*4+r, col = n0+wc*64+j*16+lr
#pragma unroll
  for (int i = 0; i < 4; ++i) {
    const int rowb = m0 + wr * 64 + i * 16 + lg * 4;
#pragma unroll
    for (int j = 0; j < 4; ++j) {
      const int col = n0 + wc * 64 + j * 16 + lr;
      const float bv = bias[col];
      if (col < 2 * DMODEL) {
        const float qs = (col < DMODEL) ? QSCALE : 1.0f;
#pragma unroll
        for (int r = 0; r < 4; ++r)
          qkb[(size_t)(rowb + r) * (2 * DMODEL) + col] =
              f2bf((acc[i][j][r] + bv) * qs);
      } else {
        const int hd = col - 2 * DMODEL;
        const int b = rowb >> 11, s0 = rowb & (SEQ - 1);
        u16x4 pk;
#pragma unroll
        for (int r = 0; r < 4; ++r) pk[r] = f2bf(acc[i][j][r] + bv);
        *(u16x4*)(vtb +
                  ((size_t)((b * NHEADS + (hd >> 6)) * HDIM + (hd & 63))) * SEQ +
                  s0) = pk;
      }
    }
  }
}

// ---------------- proj GEMM, 8 waves: C = A @ Bt^T + bias (fp32 out) ------
// 128x128 tile, BK=32, 8 waves (2Mx4N), wave-tile 64x32, acc[4][2].
// 512 threads stage a full 8KB tile in ONE gload_lds16 pass -> 2 VMEM/stage.
// Grid 256 blocks x 8 waves = 8 waves/CU = 2/SIMD (was 1/SIMD at 4 waves).
__global__ __launch_bounds__(512) void gemm_proj(
    const u16* __restrict__ A, const u16* __restrict__ Bt,
    const float* __restrict__ bias, float* __restrict__ outf,
    int M, int N, int K) {
  __shared__ __align__(16) u16 lds[3 * 2 * 4096];  // [buf][A/B][128*32] 48KB
  const int nwgx = gridDim.x;
  const int nwg = nwgx * gridDim.y;
  const int idx = blockIdx.y * nwgx + blockIdx.x;
  const int swz = (idx & 7) * (nwg >> 3) + (idx >> 3);
  const int m0 = (swz / nwgx) * 128, n0 = (swz % nwgx) * 128;

  const int tid = threadIdx.x;
  const int lane = tid & 63, w = tid >> 6;
  const int wr = w >> 2, wc = w & 3;          // 2 x 4 wave grid
  const int lg = lane >> 4, lr = lane & 15;
  const int NK = K >> 5;

  f32x4 acc[4][2] = {};

  const int srow = tid >> 2;        // 0..127 staging row
  const int scb = (tid & 3) << 4;   // staging byte col 0..48
  const char* Abase = (const char*)A + ((size_t)(m0 + srow) * K) * 2 + scb;
  const char* Bbase = (const char*)Bt + ((size_t)(n0 + srow) * K) * 2 + scb;

  auto stage = [&](int buf, int kk) {  // 2 VMEM ops per wave
    char* dst = (char*)lds + buf * 16384;
    gload_lds16(Abase + kk * 64, dst + tid * 16);
    gload_lds16(Bbase + kk * 64, dst + 8192 + tid * 16);
  };

  stage(0, 0);
  stage(1, 1);
  int bi = 0;
  for (int kk = 0; kk < NK; ++kk) {
    // stage(kk) is followed by exactly 2 VMEM ops (stage(kk+1)) when kk<NK-1.
    if (kk < NK - 1) WAIT_VM2(); else WAIT_VM0();
    __builtin_amdgcn_s_barrier();
    if (kk + 2 < NK) stage(bi == 0 ? 2 : bi - 1, kk + 2);
    const u16* lA = lds + bi * 8192;
    const u16* lB = lA + 4096;
    bf16x8 af[4], bfr[2];
#pragma unroll
    for (int i = 0; i < 4; ++i)
      af[i] = *(const bf16x8*)(lA + (wr * 64 + i * 16 + lr) * 32 + lg * 8);
#pragma unroll
    for (int j = 0; j < 2; ++j)
      bfr[j] = *(const bf16x8*)(lB + (wc * 32 + j * 16 + lr) * 32 + lg * 8);
#pragma unroll
    for (int i = 0; i < 4; ++i)
#pragma unroll
      for (int j = 0; j < 2; ++j)
        acc[i][j] = __builtin_amdgcn_mfma_f32_16x16x32_bf16(af[i], bfr[j],
                                                            acc[i][j], 0, 0, 0);
    bi = (bi == 2) ? 0 : bi + 1;
  }

  // epilogue: row = m0+wr*64+i*16+lg*4+r, col = n0+wc*32+j*16+lr
#pragma unroll
  for (int i = 0; i < 4; ++i) {
    const int rowb = m0 + wr * 64 + i * 16 + lg * 4;
#pragma unroll
    for (int j = 0; j < 2; ++j) {
      const int col = n0 + wc * 32 + j * 16 + lr;
      const float bv = bias[col];
#pragma unroll
      for (int r = 0; r < 4; ++r)
        outf[(size_t)(rowb + r) * N + col] = acc[i][j][r] + bv;
    }
  }
}

// ---------------- flash attention, 32x32 swapped-QK^T, sw-pipelined --------
// grid 512 swizzled (q-tile 128, 16 heads, 2 batch), 256 thr = 4 waves.
// qkb: [4096][2048] bf16 (Qscaled | K), vtb: [B][H][64][SEQ] bf16 (V^T).
// Per lane: one q-row (q = lane&31), hi = lane>>5 selects k-halves.
// Iter t: issue QKT(t) + PV(t-1) on matrix pipe, then softmax(t) on VALU.
// K LDS mod-3 (lifetime t..t+2), V LDS mod-4 (lifetime t-1..t+2). 56KB total.
// Measured: 60.7us, MfmaUtil 22%, VALUBusy 47% (R9 bench).
__global__ __launch_bounds__(256) void attn(const u16* __restrict__ qkb,
                                            const u16* __restrict__ vtb,
                                            const int* __restrict__ mask,
                                            u16* __restrict__ ctxb) {
  __shared__ __align__(16) u16 Kl[3][64 * 64];  // 24KB (swizzled rows)
  __shared__ __align__(16) u16 Vl[4][64 * 64];  // 32KB (swizzled rows)

  const int idx = (blockIdx.z * gridDim.y + blockIdx.y) * gridDim.x + blockIdx.x;
  const int swz = (idx & 7) * 64 + (idx >> 3);
  const int q0 = (swz & 15) * 128;
  const int h = (swz >> 4) & 15;
  const int b = swz >> 8;

  const int tid = threadIdx.x;
  const int lane = tid & 63, w = tid >> 6;
  const int qi = lane & 31;            // lane's q-row
  const int hi = lane >> 5;            // half-wave (k-split)
  const int q = q0 + w * 32 + qi;

  // ---- mask prescan, register-only ----
  bool anyz;
  {
    const int4* mrow = (const int4*)(mask + b * SEQ);
    int z = 0;
#pragma unroll
    for (int p = 0; p < 8; ++p) {
      int4 m = mrow[lane + p * 64];
      z |= (m.x == 0) | (m.y == 0) | (m.z == 0) | (m.w == 0);
    }
    anyz = __any(z);
  }

  // Q regs: B-operand fragments over d (4 chunks of K=16)
  bf16x8 qreg[4];
  {
    const u16* Qrow = qkb + (size_t)(b * SEQ + q) * (2 * DMODEL) + h * HDIM;
#pragma unroll
    for (int kc = 0; kc < 4; ++kc)
      qreg[kc] = *(const bf16x8*)(Qrow + kc * 16 + hi * 8);
  }

  float m_run = -3.0e38f, l_run = 0.f;
  f32x16 ct0 = (f32x16)0.f, ct1 = (f32x16)0.f;   // ctx^T: d=qi(+32), cols=q

  const u16* Kg = qkb + (size_t)(b * SEQ) * (2 * DMODEL) + DMODEL + h * HDIM;
  const u16* Vg = vtb + (size_t)((b * NHEADS + h) * HDIM) * SEQ;
  const int srow = tid >> 3;                          // staging row 0..31 (+32)
  const int scol = ((tid & 7) ^ (srow & 7)) << 4;     // pre-swizzled src byte col

  auto stage = [&](int t) {  // 4 VMEM ops per wave
    const int kb = t % 3, vb = t & 3;
    const int k0 = t * 64;
    const char* ks = (const char*)(Kg + (size_t)(k0 + srow) * (2 * DMODEL)) + scol;
    gload_lds16(ks, (char*)Kl[kb] + tid * 16);
    gload_lds16(ks + (size_t)32 * (2 * DMODEL) * 2,
                (char*)Kl[kb] + 4096 + tid * 16);
    const char* vs = (const char*)(Vg + (size_t)srow * SEQ + k0) + scol;
    gload_lds16(vs, (char*)Vl[vb] + tid * 16);
    gload_lds16(vs + (size_t)32 * SEQ * 2, (char*)Vl[vb] + 4096 + tid * 16);
  };

  auto qkt = [&](int t, f32x16& s0, f32x16& s1) {
    const char* Kb = (const char*)Kl[t % 3];
    __builtin_amdgcn_s_setprio(1);
#pragma unroll
    for (int kc = 0; kc < 4; ++kc) {
      const int sl = (((kc << 1) | hi) ^ (lane & 7)) << 4;
      bf16x8 kf0 = *(const bf16x8*)(Kb + qi * 128 + sl);
      bf16x8 kf1 = *(const bf16x8*)(Kb + (32 + qi) * 128 + sl);
      s0 = __builtin_amdgcn_mfma_f32_32x32x16_bf16(kf0, qreg[kc], s0, 0, 0, 0);
      s1 = __builtin_amdgcn_mfma_f32_32x32x16_bf16(kf1, qreg[kc], s1, 0, 0, 0);
    }
    __builtin_amdgcn_s_setprio(0);
  };

  auto pv = [&](int t, const unsigned pk[16]) {
    const char* Vb = (const char*)Vl[t & 3];
    __builtin_amdgcn_s_setprio(1);
#pragma unroll
    for (int ks = 0; ks < 4; ++ks) {
      const int mb = (ks >> 1) * 8 + (ks & 1) * 4;
      unsigned b0 = pk[mb + 0], b2 = pk[mb + 2];
      unsigned b1 = pk[mb + 1], b3 = pk[mb + 3];
      pl32swap(b0, b2);   // b0 = both lo-halves, b2 = both hi-halves
      pl32swap(b1, b3);
      union { unsigned u[4]; bf16x8 v; } bu;
      bu.u[0] = b0; bu.u[1] = b1; bu.u[2] = b2; bu.u[3] = b3;
      const int sl = (((ks << 1) | hi) ^ (lane & 7)) << 4;
      bf16x8 vf0 = *(const bf16x8*)(Vb + qi * 128 + sl);
      bf16x8 vf1 = *(const bf16x8*)(Vb + (32 + qi) * 128 + sl);
      ct0 = __builtin_amdgcn_mfma_f32_32x32x16_bf16(vf0, bu.v, ct0, 0, 0, 0);
      ct1 = __builtin_amdgcn_mfma_f32_32x32x16_bf16(vf1, bu.v, ct1, 0, 0, 0);
    }
    __builtin_amdgcn_s_setprio(0);
  };

  auto softmax = [&](f32x16& s0, f32x16& s1, int t, bool use_mask,
                     unsigned pk[16]) {
    if (use_mask) {
      const int base = b * SEQ + t * 64;
#pragma unroll
      for (int r = 0; r < 16; ++r) {
        const int key = (r & 3) + 8 * (r >> 2) + 4 * hi;
        if (mask[base + key] == 0) s0[r] = -3.0e38f;
        if (mask[base + 32 + key] == 0) s1[r] = -3.0e38f;
      }
    }
    float pm = fmaxf(fmaxf(s0[0], s0[1]), s0[2]);
#pragma unroll
    for (int r = 3; r < 16; r += 2) pm = fmaxf(fmaxf(pm, s0[r]), s0[r + 1]);
#pragma unroll
    for (int r = 0; r < 16; r += 2) pm = fmaxf(fmaxf(pm, s1[r]), s1[r + 1]);
    pm = fmaxf(pm, __shfl_xor(pm, 32));
    if (__any(pm > m_run + 8.f)) {
      const float mn = fmaxf(m_run, pm);
      const float corr = __builtin_amdgcn_exp2f(m_run - mn);
      m_run = mn;
      l_run *= corr;
#pragma unroll
      for (int r = 0; r < 16; ++r) { ct0[r] *= corr; ct1[r] *= corr; }
    }
    float ls = 0.f;
#pragma unroll
    for (int r = 0; r < 16; ++r) {
      s0[r] = __builtin_amdgcn_exp2f(s0[r] - m_run); ls += s0[r];
    }
#pragma unroll
    for (int r = 0; r < 16; ++r) {
      s1[r] = __builtin_amdgcn_exp2f(s1[r] - m_run); ls += s1[r];
    }
    l_run += ls + __shfl_xor(ls, 32);
#pragma unroll
    for (int rp = 0; rp < 8; ++rp) {
      pk[rp] = cvtpk(s0[2 * rp], s0[2 * rp + 1]);
      pk[8 + rp] = cvtpk(s1[2 * rp], s1[2 * rp + 1]);
    }
  };

  const int NT = SEQ / 64;
  unsigned pkp[16];
  stage(0);
  stage(1);
  if (!anyz) {
    WAIT_VM4();                      // stage(0) done (stage(1) in flight)
    __builtin_amdgcn_s_barrier();
    stage(2);
    {
      f32x16 s0 = (f32x16)0.f, s1 = (f32x16)0.f;
      qkt(0, s0, s1);
      softmax(s0, s1, 0, false, pkp);
    }
    for (int t = 1; t < NT; ++t) {
      if (t < NT - 1) WAIT_VM4(); else WAIT_VM0();   // stage(t) done
      __builtin_amdgcn_s_barrier();
      if (t + 2 < NT) stage(t + 2);
      f32x16 s0 = (f32x16)0.f, s1 = (f32x16)0.f;
      qkt(t, s0, s1);
      pv(t - 1, pkp);
      softmax(s0, s1, t, false, pkp);
    }
    pv(NT - 1, pkp);
  } else {
    for (int t = 0; t < NT; ++t) {
      __syncthreads();
      if (t + 2 < NT) stage(t + 2);
      __syncthreads();
      f32x16 s0 = (f32x16)0.f, s1 = (f32x16)0.f;
      qkt(t, s0, s1);
      softmax(s0, s1, t, true, pkp);
      pv(t, pkp);
    }
  }

  // ---- epilogue: ctx^T / l -> ctxb[token][DMODEL] bf16 ----
  const float rl = __builtin_amdgcn_rcpf(l_run);
  u16* orow = ctxb + (size_t)(b * SEQ + q) * DMODEL + h * HDIM;
#pragma unroll
  for (int g = 0; g < 4; ++g) {
    {
      const int d0 = 8 * g + 4 * hi;
      uint2 st;
      st.x = cvtpk(ct0[4 * g] * rl, ct0[4 * g + 1] * rl);
      st.y = cvtpk(ct0[4 * g + 2] * rl, ct0[4 * g + 3] * rl);
      *(uint2*)(orow + d0) = st;
    }
    {
      const int d0 = 32 + 8 * g + 4 * hi;
      uint2 st;
      st.x = cvtpk(ct1[4 * g] * rl, ct1[4 * g + 1] * rl);
      st.y = cvtpk(ct1[4 * g + 2] * rl, ct1[4 * g + 3] * rl);
      *(uint2*)(orow + d0) = st;
    }
  }
}

extern "C" void kernel_launch(void* const* d_in, const int* in_sizes, int n_in,
                              void* d_out, int out_size, void* d_ws, size_t ws_size,
                              hipStream_t stream) {
  const float* x = (const float*)d_in[0];
  const int* mask = (const int*)d_in[1];
  const float* Wqkv = (const float*)d_in[2];
  const float* bqkv = (const float*)d_in[3];
  const float* Wproj = (const float*)d_in[4];
  const float* bproj = (const float*)d_in[5];
  float* out = (float*)d_out;

  char* ws = (char*)d_ws;
  u16* xb = (u16*)(ws);                       // 4096*1024 bf16      (8 MB)
  u16* wqkvt = (u16*)(ws + 8388608);          // [3072][1024] bf16   (6 MB)
  u16* wprojt = (u16*)(ws + 14680064);        // [1024][1024] bf16   (2 MB)
  u16* qkb = (u16*)(ws + 16777216);           // [4096][2048] bf16   (16 MB)
  u16* vtb = (u16*)(ws + 33554432);           // [B][H][64][2048]    (8 MB)
  u16* ctxb = (u16*)(ws + 41943040);          // [4096][1024] bf16   (8 MB)

  conv_x<<<dim3((BS * DMODEL / 4 + 255) / 256), 256, 0, stream>>>(x, xb,
                                                                  BS * DMODEL / 4);
  transp<<<dim3(N3 / 64, DMODEL / 64), 256, 0, stream>>>(Wqkv, wqkvt, DMODEL, N3);
  transp<<<dim3(DMODEL / 64, DMODEL / 64), 256, 0, stream>>>(Wproj, wprojt, DMODEL,
                                                             DMODEL);
  gemm_qkv<<<dim3(N3 / 128, BS / 128), 256, 0, stream>>>(
      xb, wqkvt, bqkv, qkb, vtb, BS, N3, DMODEL);
  attn<<<dim3(SEQ / 128, NHEADS, BATCH), 256, 0, stream>>>(qkb, vtb, mask, ctxb);
  gemm_proj<<<dim3(DMODEL / 128, BS / 128), 512, 0, stream>>>(
      ctxb, wprojt, bproj, out, BS, DMODEL, DMODEL);
}